// Round 2
// baseline (484.583 us; speedup 1.0000x reference)
//
#include <hip/hip_runtime.h>
#include <math.h>

#define B_    4
#define N_    16384
#define S_    1024
#define C1_   128
#define C2_   256
#define CIN_  384
#define H1_   256
#define H2_   128
#define BN_EPS_    1e-5f
#define INTERP_EPS_ 1e-8f

#define BM 64
#define BN 64
#define BKK 16

// ---------------------------------------------------------------------------
// Kernel 1: per-point top-3 nearest neighbors (fp64 distances for exact
// ordering vs the f64 numpy reference) + inverse-distance weights (f32,
// matching the reference formula).
// ---------------------------------------------------------------------------
__global__ __launch_bounds__(256) void topk_kernel(
    const float* __restrict__ xyz1, const float* __restrict__ xyz2,
    int* __restrict__ idx_out, float* __restrict__ w_out)
{
    __shared__ float q[S_ * 3];
    const int b     = blockIdx.x >> 6;          // 64 blocks of 256 points per batch
    const int nbase = (blockIdx.x & 63) << 8;
    const int tid   = threadIdx.x;

    for (int i = tid; i < S_ * 3; i += 256) q[i] = xyz2[b * S_ * 3 + i];
    __syncthreads();

    const int n = nbase + tid;
    const float* p = &xyz1[((size_t)b * N_ + n) * 3];
    const double px = (double)p[0], py = (double)p[1], pz = (double)p[2];

    double d0 = 1e300, d1 = 1e300, d2 = 1e300;
    int    i0 = 0,     i1 = 0,     i2 = 0;

    for (int s = 0; s < S_; ++s) {
        const double dx = px - (double)q[s * 3 + 0];
        const double dy = py - (double)q[s * 3 + 1];
        const double dz = pz - (double)q[s * 3 + 2];
        const double d  = dx * dx + dy * dy + dz * dz;
        if (d < d2) {
            if (d < d1) {
                if (d < d0) { d2 = d1; i2 = i1; d1 = d0; i1 = i0; d0 = d; i0 = s; }
                else        { d2 = d1; i2 = i1; d1 = d;  i1 = s; }
            } else          { d2 = d;  i2 = s; }
        }
    }

    const float r0 = 1.0f / ((float)d0 + INTERP_EPS_);
    const float r1 = 1.0f / ((float)d1 + INTERP_EPS_);
    const float r2 = 1.0f / ((float)d2 + INTERP_EPS_);
    const float rs = r0 + r1 + r2;

    const int base = (b * N_ + n) * 3;
    idx_out[base + 0] = i0; idx_out[base + 1] = i1; idx_out[base + 2] = i2;
    w_out[base + 0] = r0 / rs; w_out[base + 1] = r1 / rs; w_out[base + 2] = r2 / rs;
}

// ---------------------------------------------------------------------------
// Kernel 2: fused {interpolation gather, concat, GEMM1 (65536x384 @ 384x256),
// BN+ReLU} -> h.  64x64 tile, BK=16, 256 threads, 4x4 micro-tile.
// ---------------------------------------------------------------------------
__global__ __launch_bounds__(256) void gemm1_kernel(
    const float* __restrict__ points1, const float* __restrict__ points2,
    const int* __restrict__ idx, const float* __restrict__ wts,
    const float* __restrict__ w1,
    const float* __restrict__ g1, const float* __restrict__ b1,
    const float* __restrict__ m1, const float* __restrict__ v1,
    float* __restrict__ h)
{
    __shared__ float As[BKK][BM];
    __shared__ float Bs[BKK][BN];

    const int rowbase = blockIdx.x * BM;     // 1024 row blocks
    const int colbase = blockIdx.y * BN;     // 4 col blocks
    const int tid = threadIdx.x;
    const int tx = tid & 15, ty = tid >> 4;

    // staging role: 4 threads per row, each stages 4 consecutive k
    const int sr = tid >> 2;
    const int sk = (tid & 3) * 4;
    const int R  = rowbase + sr;
    const int b  = R >> 14;                  // /16384

    // hoist this row's interpolation metadata
    int i3_0, i3_1, i3_2; float w3_0, w3_1, w3_2;
    {
        const int base = R * 3;
        i3_0 = idx[base]; i3_1 = idx[base + 1]; i3_2 = idx[base + 2];
        w3_0 = wts[base]; w3_1 = wts[base + 1]; w3_2 = wts[base + 2];
    }
    const float* p2b = points2 + (size_t)b * S_ * C2_;

    float acc[4][4] = {};

    for (int kb = 0; kb < CIN_; kb += BKK) {
        __syncthreads();
        const int k = kb + sk;
        float4 av;
        if (k < C1_) {
            av = *(const float4*)&points1[(size_t)R * C1_ + k];
        } else {
            const int c = k - C1_;
            const float4 f0 = *(const float4*)&p2b[(size_t)i3_0 * C2_ + c];
            const float4 f1 = *(const float4*)&p2b[(size_t)i3_1 * C2_ + c];
            const float4 f2 = *(const float4*)&p2b[(size_t)i3_2 * C2_ + c];
            av.x = w3_0 * f0.x + w3_1 * f1.x + w3_2 * f2.x;
            av.y = w3_0 * f0.y + w3_1 * f1.y + w3_2 * f2.y;
            av.z = w3_0 * f0.z + w3_1 * f1.z + w3_2 * f2.z;
            av.w = w3_0 * f0.w + w3_1 * f1.w + w3_2 * f2.w;
        }
        As[sk + 0][sr] = av.x; As[sk + 1][sr] = av.y;
        As[sk + 2][sr] = av.z; As[sk + 3][sr] = av.w;

        const float4 bv = *(const float4*)&w1[(size_t)(colbase + sr) * CIN_ + k];
        Bs[sk + 0][sr] = bv.x; Bs[sk + 1][sr] = bv.y;
        Bs[sk + 2][sr] = bv.z; Bs[sk + 3][sr] = bv.w;
        __syncthreads();

        #pragma unroll
        for (int kk = 0; kk < BKK; ++kk) {
            const float4 a  = *(const float4*)&As[kk][ty * 4];
            const float4 bb = *(const float4*)&Bs[kk][tx * 4];
            acc[0][0] += a.x * bb.x; acc[0][1] += a.x * bb.y; acc[0][2] += a.x * bb.z; acc[0][3] += a.x * bb.w;
            acc[1][0] += a.y * bb.x; acc[1][1] += a.y * bb.y; acc[1][2] += a.y * bb.z; acc[1][3] += a.y * bb.w;
            acc[2][0] += a.z * bb.x; acc[2][1] += a.z * bb.y; acc[2][2] += a.z * bb.z; acc[2][3] += a.z * bb.w;
            acc[3][0] += a.w * bb.x; acc[3][1] += a.w * bb.y; acc[3][2] += a.w * bb.z; acc[3][3] += a.w * bb.w;
        }
    }

    float sc[4], sh[4];
    #pragma unroll
    for (int j = 0; j < 4; ++j) {
        const int c = colbase + tx * 4 + j;
        const float s = g1[c] / sqrtf(v1[c] + BN_EPS_);
        sc[j] = s; sh[j] = b1[c] - m1[c] * s;
    }
    #pragma unroll
    for (int i = 0; i < 4; ++i) {
        const int row = rowbase + ty * 4 + i;
        float4 o;
        o.x = fmaxf(acc[i][0] * sc[0] + sh[0], 0.0f);
        o.y = fmaxf(acc[i][1] * sc[1] + sh[1], 0.0f);
        o.z = fmaxf(acc[i][2] * sc[2] + sh[2], 0.0f);
        o.w = fmaxf(acc[i][3] * sc[3] + sh[3], 0.0f);
        *(float4*)&h[(size_t)row * H1_ + colbase + tx * 4] = o;
    }
}

// ---------------------------------------------------------------------------
// Kernel 3: GEMM2 (65536x256 @ 256x128) + BN + ReLU -> out
// ---------------------------------------------------------------------------
__global__ __launch_bounds__(256) void gemm2_kernel(
    const float* __restrict__ hin, const float* __restrict__ w2,
    const float* __restrict__ g2, const float* __restrict__ b2,
    const float* __restrict__ m2, const float* __restrict__ v2,
    float* __restrict__ out)
{
    __shared__ float As[BKK][BM];
    __shared__ float Bs[BKK][BN];

    const int rowbase = blockIdx.x * BM;     // 1024 row blocks
    const int colbase = blockIdx.y * BN;     // 2 col blocks
    const int tid = threadIdx.x;
    const int tx = tid & 15, ty = tid >> 4;
    const int sr = tid >> 2;
    const int sk = (tid & 3) * 4;
    const int R  = rowbase + sr;

    float acc[4][4] = {};

    for (int kb = 0; kb < H1_; kb += BKK) {
        __syncthreads();
        const int k = kb + sk;
        const float4 av = *(const float4*)&hin[(size_t)R * H1_ + k];
        As[sk + 0][sr] = av.x; As[sk + 1][sr] = av.y;
        As[sk + 2][sr] = av.z; As[sk + 3][sr] = av.w;

        const float4 bv = *(const float4*)&w2[(size_t)(colbase + sr) * H1_ + k];
        Bs[sk + 0][sr] = bv.x; Bs[sk + 1][sr] = bv.y;
        Bs[sk + 2][sr] = bv.z; Bs[sk + 3][sr] = bv.w;
        __syncthreads();

        #pragma unroll
        for (int kk = 0; kk < BKK; ++kk) {
            const float4 a  = *(const float4*)&As[kk][ty * 4];
            const float4 bb = *(const float4*)&Bs[kk][tx * 4];
            acc[0][0] += a.x * bb.x; acc[0][1] += a.x * bb.y; acc[0][2] += a.x * bb.z; acc[0][3] += a.x * bb.w;
            acc[1][0] += a.y * bb.x; acc[1][1] += a.y * bb.y; acc[1][2] += a.y * bb.z; acc[1][3] += a.y * bb.w;
            acc[2][0] += a.z * bb.x; acc[2][1] += a.z * bb.y; acc[2][2] += a.z * bb.z; acc[2][3] += a.z * bb.w;
            acc[3][0] += a.w * bb.x; acc[3][1] += a.w * bb.y; acc[3][2] += a.w * bb.z; acc[3][3] += a.w * bb.w;
        }
    }

    float sc[4], sh[4];
    #pragma unroll
    for (int j = 0; j < 4; ++j) {
        const int c = colbase + tx * 4 + j;
        const float s = g2[c] / sqrtf(v2[c] + BN_EPS_);
        sc[j] = s; sh[j] = b2[c] - m2[c] * s;
    }
    #pragma unroll
    for (int i = 0; i < 4; ++i) {
        const int row = rowbase + ty * 4 + i;
        float4 o;
        o.x = fmaxf(acc[i][0] * sc[0] + sh[0], 0.0f);
        o.y = fmaxf(acc[i][1] * sc[1] + sh[1], 0.0f);
        o.z = fmaxf(acc[i][2] * sc[2] + sh[2], 0.0f);
        o.w = fmaxf(acc[i][3] * sc[3] + sh[3], 0.0f);
        *(float4*)&out[(size_t)row * H2_ + colbase + tx * 4] = o;
    }
}

// ---------------------------------------------------------------------------
extern "C" void kernel_launch(void* const* d_in, const int* in_sizes, int n_in,
                              void* d_out, int out_size, void* d_ws, size_t ws_size,
                              hipStream_t stream) {
    const float* xyz1    = (const float*)d_in[0];
    const float* xyz2    = (const float*)d_in[1];
    const float* points1 = (const float*)d_in[2];
    const float* points2 = (const float*)d_in[3];
    const float* w1      = (const float*)d_in[4];
    const float* g1      = (const float*)d_in[5];
    const float* b1      = (const float*)d_in[6];
    const float* m1      = (const float*)d_in[7];
    const float* v1      = (const float*)d_in[8];
    const float* w2      = (const float*)d_in[9];
    const float* g2      = (const float*)d_in[10];
    const float* b2      = (const float*)d_in[11];
    const float* m2      = (const float*)d_in[12];
    const float* v2      = (const float*)d_in[13];
    float* out = (float*)d_out;

    // ws layout: idx (65536*3 int) | wts (65536*3 f32) | h (65536*256 f32) = ~69 MB
    int*   idx_ws = (int*)d_ws;
    float* w_ws   = (float*)d_ws + (size_t)B_ * N_ * 3;
    float* h_ws   = (float*)d_ws + (size_t)B_ * N_ * 6;

    topk_kernel<<<dim3(B_ * N_ / 256), dim3(256), 0, stream>>>(xyz1, xyz2, idx_ws, w_ws);
    gemm1_kernel<<<dim3(B_ * N_ / BM, H1_ / BN), dim3(256), 0, stream>>>(
        points1, points2, idx_ws, w_ws, w1, g1, b1, m1, v1, h_ws);
    gemm2_kernel<<<dim3(B_ * N_ / BM, H2_ / BN), dim3(256), 0, stream>>>(
        h_ws, w2, g2, b2, m2, v2, out);
}

// Round 3
// 206.425 us; speedup vs baseline: 2.3475x; 2.3475x over previous
//
#include <hip/hip_runtime.h>
#include <math.h>

#define B_    4
#define N_    16384
#define S_    1024
#define C1_   128
#define C2_   256
#define CIN_  384
#define H1_   256
#define H2_   128
#define BN_EPS_     1e-5f
#define INTERP_EPS_ 1e-8f

typedef _Float16 f16;
typedef _Float16 f16x4 __attribute__((ext_vector_type(4)));
typedef _Float16 f16x8 __attribute__((ext_vector_type(8)));
typedef float    f32x4 __attribute__((ext_vector_type(4)));

// async global->LDS, 16B per lane; LDS dest = wave-uniform base + lane*16
#define GLD16(g, l) \
  __builtin_amdgcn_global_load_lds((const __attribute__((address_space(1))) void*)(g), \
                                   (__attribute__((address_space(3))) void*)(l), 16, 0, 0)

// ---- ws layout (bytes) ----
#define WS_IDX 0            // 196608 int
#define WS_W   786432       // 196608 f32
#define WS_H   1572864      // 16777216 f16 (h, [65536][256])
#define WS_W1F 35127296     // 98304 f16
#define WS_W2F 35323904     // 32768 f16
#define WS_SC1 35389440     // 256 f32
#define WS_SH1 35390464
#define WS_SC2 35391488     // 128 f32
#define WS_SH2 35392000

// ---------------------------------------------------------------------------
// prep: w1,w2 -> f16; fold BN into (scale, shift)
// ---------------------------------------------------------------------------
__global__ __launch_bounds__(256) void prep_kernel(
    const float* __restrict__ w1, const float* __restrict__ w2,
    const float* __restrict__ g1, const float* __restrict__ b1,
    const float* __restrict__ m1, const float* __restrict__ v1,
    const float* __restrict__ g2, const float* __restrict__ b2,
    const float* __restrict__ m2, const float* __restrict__ v2,
    f16* __restrict__ w1f, f16* __restrict__ w2f,
    float* __restrict__ sc1, float* __restrict__ sh1,
    float* __restrict__ sc2, float* __restrict__ sh2)
{
    const int t = blockIdx.x * 256 + threadIdx.x;
    if (t < 98304) {
        w1f[t] = (f16)w1[t];
    } else if (t < 131072) {
        w2f[t - 98304] = (f16)w2[t - 98304];
    } else if (t < 131328) {
        const int c = t - 131072;
        const float s = g1[c] / sqrtf(v1[c] + BN_EPS_);
        sc1[c] = s; sh1[c] = b1[c] - m1[c] * s;
    } else if (t < 131456) {
        const int c = t - 131328;
        const float s = g2[c] / sqrtf(v2[c] + BN_EPS_);
        sc2[c] = s; sh2[c] = b2[c] - m2[c] * s;
    }
}

// ---------------------------------------------------------------------------
// topk: 4 threads/point, f32 scan of 256 candidates each keeping top-4,
// shuffle-merge, then f64 refine of the 4 survivors (exact ordering vs np).
// ---------------------------------------------------------------------------
#define LESS_(e, ei, dj, ij) ((e) < (dj) || ((e) == (dj) && (ei) < (ij)))
#define INSERT_LEX(e, ei) do { \
    if (LESS_(e, ei, d[3], id[3])) { \
      if (LESS_(e, ei, d[2], id[2])) { d[3] = d[2]; id[3] = id[2]; \
        if (LESS_(e, ei, d[1], id[1])) { d[2] = d[1]; id[2] = id[1]; \
          if (LESS_(e, ei, d[0], id[0])) { d[1] = d[0]; id[1] = id[0]; d[0] = e; id[0] = ei; } \
          else { d[1] = e; id[1] = ei; } } \
        else { d[2] = e; id[2] = ei; } } \
      else { d[3] = e; id[3] = ei; } } } while (0)
#define CSWAP(a_, b_) do { \
    if (rd[b_] < rd[a_] || (rd[b_] == rd[a_] && ri[b_] < ri[a_])) { \
      double td = rd[a_]; rd[a_] = rd[b_]; rd[b_] = td; \
      int ti = ri[a_]; ri[a_] = ri[b_]; ri[b_] = ti; } } while (0)

// q layout: float4 per point + 16B stagger per 256-chunk to kill the 4-way
// bank aliasing of the 4 chunk readers (chunk j offset = j*4 floats)
__device__ __forceinline__ int qaddr(int s) { return s * 4 + (s >> 8) * 4; }

__global__ __launch_bounds__(256) void topk_kernel(
    const float* __restrict__ xyz1, const float* __restrict__ xyz2,
    int* __restrict__ idx_out, float* __restrict__ w_out)
{
    __shared__ float q[4128];
    const int b     = blockIdx.x >> 8;           // 256 blocks/batch, 64 pts each
    const int pbase = (blockIdx.x & 255) << 6;
    const int t     = threadIdx.x;

    for (int i = t; i < S_; i += 256) {
        const float* s = &xyz2[((size_t)b * S_ + i) * 3];
        const int a = qaddr(i);
        q[a] = s[0]; q[a + 1] = s[1]; q[a + 2] = s[2];
    }
    __syncthreads();

    const int p     = pbase + (t >> 2);
    const int chunk = t & 3;
    const float* pp = &xyz1[((size_t)b * N_ + p) * 3];
    const float px = pp[0], py = pp[1], pz = pp[2];

    float d[4] = {1e30f, 1e30f, 1e30f, 1e30f};
    int  id[4] = {0, 0, 0, 0};

    const int s0 = chunk << 8;
    for (int s = s0; s < s0 + 256; ++s) {
        const int a = qaddr(s);
        const float dx = px - q[a], dy = py - q[a + 1], dz = pz - q[a + 2];
        const float dd = fmaf(dx, dx, fmaf(dy, dy, dz * dz));
        if (dd < d[3]) {             // indices ascending -> strict < is stable
            if (dd < d[2]) { d[3] = d[2]; id[3] = id[2];
                if (dd < d[1]) { d[2] = d[1]; id[2] = id[1];
                    if (dd < d[0]) { d[1] = d[0]; id[1] = id[0]; d[0] = dd; id[0] = s; }
                    else { d[1] = dd; id[1] = s; } }
                else { d[2] = dd; id[2] = s; } }
            else { d[3] = dd; id[3] = s; }
        }
    }

    #pragma unroll
    for (int msk = 1; msk <= 2; msk <<= 1) {
        float e0 = __shfl_xor(d[0], msk), e1 = __shfl_xor(d[1], msk);
        float e2 = __shfl_xor(d[2], msk), e3 = __shfl_xor(d[3], msk);
        int   j0 = __shfl_xor(id[0], msk), j1 = __shfl_xor(id[1], msk);
        int   j2 = __shfl_xor(id[2], msk), j3 = __shfl_xor(id[3], msk);
        INSERT_LEX(e0, j0); INSERT_LEX(e1, j1); INSERT_LEX(e2, j2); INSERT_LEX(e3, j3);
    }

    if (chunk == 0) {
        const double px6 = px, py6 = py, pz6 = pz;
        double rd[4]; int ri[4];
        #pragma unroll
        for (int j = 0; j < 4; ++j) {
            const int s = id[j]; ri[j] = s;
            const int a = qaddr(s);
            const double dx = px6 - (double)q[a], dy = py6 - (double)q[a + 1], dz = pz6 - (double)q[a + 2];
            rd[j] = dx * dx + dy * dy + dz * dz;
        }
        CSWAP(0, 1); CSWAP(2, 3); CSWAP(0, 2); CSWAP(1, 3); CSWAP(1, 2);
        const float f0 = (float)rd[0], f1 = (float)rd[1], f2 = (float)rd[2];
        const float r0 = 1.0f / (f0 + INTERP_EPS_);
        const float r1 = 1.0f / (f1 + INTERP_EPS_);
        const float r2 = 1.0f / (f2 + INTERP_EPS_);
        const float rs = r0 + r1 + r2;
        const int base = (b * N_ + p) * 3;
        idx_out[base] = ri[0]; idx_out[base + 1] = ri[1]; idx_out[base + 2] = ri[2];
        w_out[base] = r0 / rs; w_out[base + 1] = r1 / rs; w_out[base + 2] = r2 / rs;
    }
}

// ---------------------------------------------------------------------------
// gemm1: fused {interp-gather, concat, GEMM 65536x384 @ w1^T, BN+ReLU} -> h f16
// 128x256 tile, BK=32, 4 waves (2x2), wave tile 64x128, mfma_f32_16x16x32_f16
// ---------------------------------------------------------------------------
__device__ __forceinline__ void mfma_step1(const f16* As, const f16* Bs,
                                           f32x4 (&acc)[4][8],
                                           int wr, int wc, int lrow, int lhi)
{
    f16x8 af[4], bf[8];
    #pragma unroll
    for (int m = 0; m < 4; ++m)
        af[m] = *(const f16x8*)&As[(wr * 64 + m * 16 + lrow) * 32 + lhi * 8];
    #pragma unroll
    for (int n = 0; n < 8; ++n)
        bf[n] = *(const f16x8*)&Bs[(wc * 128 + n * 16 + lrow) * 32 + lhi * 8];
    #pragma unroll
    for (int m = 0; m < 4; ++m)
        #pragma unroll
        for (int n = 0; n < 8; ++n)
            acc[m][n] = __builtin_amdgcn_mfma_f32_16x16x32_f16(af[m], bf[n], acc[m][n], 0, 0, 0);
}

__global__ __launch_bounds__(256, 2) void gemm1_kernel(
    const float* __restrict__ points1, const float* __restrict__ points2,
    const int* __restrict__ idx, const float* __restrict__ wts,
    const f16* __restrict__ w1f,
    const float* __restrict__ sc1v, const float* __restrict__ sh1v,
    f16* __restrict__ h)
{
    __shared__ __align__(16) f16 As[128 * 32];
    __shared__ __align__(16) f16 Bs[256 * 32];

    const int t = threadIdx.x;
    const int w = t >> 6;
    const int lane = t & 63;
    const int wr = w >> 1, wc = w & 1;
    const int lrow = lane & 15, lhi = lane >> 4;
    const int rowbase = blockIdx.x * 128;

    // staging role: 2 threads per row, khalf = which 16-wide k-half
    const int srow = t >> 1, khalf = t & 1;
    const int R = rowbase + srow;
    const int bb = R >> 14;
    const int mb = R * 3;
    const int i0 = idx[mb], i1 = idx[mb + 1], i2 = idx[mb + 2];
    const float w0 = wts[mb], w1w = wts[mb + 1], w2w = wts[mb + 2];
    const float* p2b = points2 + (size_t)bb * S_ * C2_;
    const float* p1r = points1 + (size_t)R * C1_;
    f16* asrow = &As[srow * 32 + khalf * 16];

    f32x4 acc[4][8] = {};

    // phase A: k in [0,128) from points1
    for (int kb = 0; kb < C1_; kb += 32) {
        __syncthreads();
        const float* src = p1r + kb + khalf * 16;
        #pragma unroll
        for (int g4 = 0; g4 < 4; ++g4) {
            const float4 v = *(const float4*)(src + g4 * 4);
            f16x4 o = {(f16)v.x, (f16)v.y, (f16)v.z, (f16)v.w};
            *(f16x4*)(asrow + g4 * 4) = o;
        }
        #pragma unroll
        for (int j = 0; j < 4; ++j) {
            const int c = j * 256 + t;
            GLD16(w1f + (size_t)(c >> 2) * CIN_ + kb + (c & 3) * 8,
                  (char*)Bs + (j * 4096 + w * 1024));
        }
        __syncthreads();
        mfma_step1(As, Bs, acc, wr, wc, lrow, lhi);
    }

    // phase B: k in [128,384) = 3-NN interpolation of points2
    for (int kb = C1_; kb < CIN_; kb += 32) {
        __syncthreads();
        const int c0 = (kb - C1_) + khalf * 16;
        #pragma unroll
        for (int g4 = 0; g4 < 4; ++g4) {
            const int c = c0 + g4 * 4;
            const float4 f0 = *(const float4*)&p2b[(size_t)i0 * C2_ + c];
            const float4 f1 = *(const float4*)&p2b[(size_t)i1 * C2_ + c];
            const float4 f2 = *(const float4*)&p2b[(size_t)i2 * C2_ + c];
            const float x = fmaf(w0, f0.x, fmaf(w1w, f1.x, w2w * f2.x));
            const float y = fmaf(w0, f0.y, fmaf(w1w, f1.y, w2w * f2.y));
            const float z = fmaf(w0, f0.z, fmaf(w1w, f1.z, w2w * f2.z));
            const float u = fmaf(w0, f0.w, fmaf(w1w, f1.w, w2w * f2.w));
            f16x4 o = {(f16)x, (f16)y, (f16)z, (f16)u};
            *(f16x4*)(asrow + g4 * 4) = o;
        }
        #pragma unroll
        for (int j = 0; j < 4; ++j) {
            const int c = j * 256 + t;
            GLD16(w1f + (size_t)(c >> 2) * CIN_ + kb + (c & 3) * 8,
                  (char*)Bs + (j * 4096 + w * 1024));
        }
        __syncthreads();
        mfma_step1(As, Bs, acc, wr, wc, lrow, lhi);
    }

    // epilogue: BN+ReLU, store f16
    #pragma unroll
    for (int n = 0; n < 8; ++n) {
        const int col = wc * 128 + n * 16 + lrow;
        const float sc = sc1v[col], sh = sh1v[col];
        #pragma unroll
        for (int m = 0; m < 4; ++m) {
            const int row0 = rowbase + wr * 64 + m * 16 + lhi * 4;
            #pragma unroll
            for (int i = 0; i < 4; ++i) {
                const float v = fmaxf(fmaf(acc[m][n][i], sc, sh), 0.0f);
                h[(size_t)(row0 + i) * H1_ + col] = (f16)v;
            }
        }
    }
}

// ---------------------------------------------------------------------------
// gemm2: 65536x256 @ w2^T + BN + ReLU -> out f32. 128x128 tile, BK=32.
// ---------------------------------------------------------------------------
__global__ __launch_bounds__(256, 2) void gemm2_kernel(
    const f16* __restrict__ hin, const f16* __restrict__ w2f,
    const float* __restrict__ sc2v, const float* __restrict__ sh2v,
    float* __restrict__ out)
{
    __shared__ __align__(16) f16 As[128 * 32];
    __shared__ __align__(16) f16 Bs[128 * 32];

    const int t = threadIdx.x;
    const int w = t >> 6;
    const int lane = t & 63;
    const int wr = w >> 1, wc = w & 1;
    const int lrow = lane & 15, lhi = lane >> 4;
    const int rowbase = blockIdx.x * 128;

    f32x4 acc[4][4] = {};

    for (int kb = 0; kb < H1_; kb += 32) {
        __syncthreads();
        #pragma unroll
        for (int j = 0; j < 2; ++j) {
            const int c = j * 256 + t;
            GLD16(hin + (size_t)(rowbase + (c >> 2)) * H1_ + kb + (c & 3) * 8,
                  (char*)As + (j * 4096 + w * 1024));
            GLD16(w2f + (size_t)(c >> 2) * H1_ + kb + (c & 3) * 8,
                  (char*)Bs + (j * 4096 + w * 1024));
        }
        __syncthreads();
        f16x8 af[4], bf[4];
        #pragma unroll
        for (int m = 0; m < 4; ++m)
            af[m] = *(const f16x8*)&As[(wr * 64 + m * 16 + lrow) * 32 + lhi * 8];
        #pragma unroll
        for (int n = 0; n < 4; ++n)
            bf[n] = *(const f16x8*)&Bs[(wc * 64 + n * 16 + lrow) * 32 + lhi * 8];
        #pragma unroll
        for (int m = 0; m < 4; ++m)
            #pragma unroll
            for (int n = 0; n < 4; ++n)
                acc[m][n] = __builtin_amdgcn_mfma_f32_16x16x32_f16(af[m], bf[n], acc[m][n], 0, 0, 0);
    }

    #pragma unroll
    for (int n = 0; n < 4; ++n) {
        const int col = wc * 64 + n * 16 + lrow;
        const float sc = sc2v[col], sh = sh2v[col];
        #pragma unroll
        for (int m = 0; m < 4; ++m) {
            const int row0 = rowbase + wr * 64 + m * 16 + lhi * 4;
            #pragma unroll
            for (int i = 0; i < 4; ++i) {
                out[(size_t)(row0 + i) * H2_ + col] = fmaxf(fmaf(acc[m][n][i], sc, sh), 0.0f);
            }
        }
    }
}

// ---------------------------------------------------------------------------
extern "C" void kernel_launch(void* const* d_in, const int* in_sizes, int n_in,
                              void* d_out, int out_size, void* d_ws, size_t ws_size,
                              hipStream_t stream) {
    const float* xyz1    = (const float*)d_in[0];
    const float* xyz2    = (const float*)d_in[1];
    const float* points1 = (const float*)d_in[2];
    const float* points2 = (const float*)d_in[3];
    const float* w1      = (const float*)d_in[4];
    const float* g1      = (const float*)d_in[5];
    const float* b1      = (const float*)d_in[6];
    const float* m1      = (const float*)d_in[7];
    const float* v1      = (const float*)d_in[8];
    const float* w2      = (const float*)d_in[9];
    const float* g2      = (const float*)d_in[10];
    const float* b2      = (const float*)d_in[11];
    const float* m2      = (const float*)d_in[12];
    const float* v2      = (const float*)d_in[13];
    float* out = (float*)d_out;

    char* ws = (char*)d_ws;
    int*   idx_ws = (int*)(ws + WS_IDX);
    float* w_ws   = (float*)(ws + WS_W);
    f16*   h_ws   = (f16*)(ws + WS_H);
    f16*   w1f    = (f16*)(ws + WS_W1F);
    f16*   w2f    = (f16*)(ws + WS_W2F);
    float* sc1    = (float*)(ws + WS_SC1);
    float* sh1    = (float*)(ws + WS_SH1);
    float* sc2    = (float*)(ws + WS_SC2);
    float* sh2    = (float*)(ws + WS_SH2);

    topk_kernel<<<dim3(B_ * 256), dim3(256), 0, stream>>>(xyz1, xyz2, idx_ws, w_ws);
    prep_kernel<<<dim3(514), dim3(256), 0, stream>>>(w1, w2, g1, b1, m1, v1,
                                                     g2, b2, m2, v2,
                                                     w1f, w2f, sc1, sh1, sc2, sh2);
    gemm1_kernel<<<dim3(512), dim3(256), 0, stream>>>(points1, points2, idx_ws, w_ws,
                                                      w1f, sc1, sh1, h_ws);
    gemm2_kernel<<<dim3(512), dim3(256), 0, stream>>>(h_ws, w2f, sc2, sh2, out);
}

// Round 6
// 204.223 us; speedup vs baseline: 2.3728x; 1.0108x over previous
//
#include <hip/hip_runtime.h>
#include <math.h>

#define B_    4
#define N_    16384
#define S_    1024
#define C1_   128
#define C2_   256
#define CIN_  384
#define H1_   256
#define H2_   128
#define BN_EPS_     1e-5f
#define INTERP_EPS_ 1e-8f

typedef _Float16 f16;
typedef _Float16 f16x4 __attribute__((ext_vector_type(4)));
typedef _Float16 f16x8 __attribute__((ext_vector_type(8)));
typedef float    f32x4 __attribute__((ext_vector_type(4)));

// async global->LDS, 16B per lane; LDS dest = wave-uniform base + lane*16
#define GLD16(g, l) \
  __builtin_amdgcn_global_load_lds((const __attribute__((address_space(1))) void*)(g), \
                                   (__attribute__((address_space(3))) void*)(l), 16, 0, 0)

// ---- ws layout (bytes) ----
#define WS_IDX 0            // 196608 int
#define WS_W   786432       // 196608 f32
#define WS_H   1572864      // 16777216 f16 (h, [65536][256])
#define WS_W1F 35127296     // 98304 f16
#define WS_W2F 35323904     // 32768 f16
#define WS_SC1 35389440     // 256 f32
#define WS_SH1 35390464
#define WS_SC2 35391488     // 128 f32
#define WS_SH2 35392000

// ---------------------------------------------------------------------------
// prep: w1,w2 -> f16; fold BN into (scale, shift)
// ---------------------------------------------------------------------------
__global__ __launch_bounds__(256) void prep_kernel(
    const float* __restrict__ w1, const float* __restrict__ w2,
    const float* __restrict__ g1, const float* __restrict__ b1,
    const float* __restrict__ m1, const float* __restrict__ v1,
    const float* __restrict__ g2, const float* __restrict__ b2,
    const float* __restrict__ m2, const float* __restrict__ v2,
    f16* __restrict__ w1f, f16* __restrict__ w2f,
    float* __restrict__ sc1, float* __restrict__ sh1,
    float* __restrict__ sc2, float* __restrict__ sh2)
{
    const int t = blockIdx.x * 256 + threadIdx.x;
    if (t < 98304) {
        w1f[t] = (f16)w1[t];
    } else if (t < 131072) {
        w2f[t - 98304] = (f16)w2[t - 98304];
    } else if (t < 131328) {
        const int c = t - 131072;
        const float s = g1[c] / sqrtf(v1[c] + BN_EPS_);
        sc1[c] = s; sh1[c] = b1[c] - m1[c] * s;
    } else if (t < 131456) {
        const int c = t - 131328;
        const float s = g2[c] / sqrtf(v2[c] + BN_EPS_);
        sc2[c] = s; sh2[c] = b2[c] - m2[c] * s;
    }
}

// ---------------------------------------------------------------------------
// topk: 8 threads/point, 128 candidates each, true-distance f32 scan
// (round-3-proven numerics). Grouped min4 + __ballot scalar branch keeps the
// insertion ladder off the hot path. Read-then-insert shuffle merge
// (round-4 bug was interleaving shfl with insert). f64 refine of survivors.
// ---------------------------------------------------------------------------
#define INSERT4(e, ei) do { \
    if ((e) < d[3]) { \
      if ((e) < d[2]) { d[3] = d[2]; id[3] = id[2]; \
        if ((e) < d[1]) { d[2] = d[1]; id[2] = id[1]; \
          if ((e) < d[0]) { d[1] = d[0]; id[1] = id[0]; d[0] = (e); id[0] = (ei); } \
          else { d[1] = (e); id[1] = (ei); } } \
        else { d[2] = (e); id[2] = (ei); } } \
      else { d[3] = (e); id[3] = (ei); } } } while (0)
#define CSWAP(a_, b_) do { \
    if (rd[b_] < rd[a_] || (rd[b_] == rd[a_] && ri[b_] < ri[a_])) { \
      double td = rd[a_]; rd[a_] = rd[b_]; rd[b_] = td; \
      int ti = ri[a_]; ri[a_] = ri[b_]; ri[b_] = ti; } } while (0)

__global__ __launch_bounds__(256) void topk_kernel(
    const float* __restrict__ xyz1, const float* __restrict__ xyz2,
    int* __restrict__ idx_out, float* __restrict__ w_out)
{
    // float4 (x,y,z,pad); +1 float4 stagger per 128-chunk tiles all 32 banks
    __shared__ float4 q[S_ + 8];
    const int b     = blockIdx.x >> 9;           // 512 blocks/batch, 32 pts each
    const int pbase = (blockIdx.x & 511) << 5;
    const int t     = threadIdx.x;

    for (int i = t; i < S_; i += 256) {
        const float* s = &xyz2[((size_t)b * S_ + i) * 3];
        float4 v; v.x = s[0]; v.y = s[1]; v.z = s[2]; v.w = 0.0f;
        q[i + (i >> 7)] = v;
    }
    __syncthreads();

    const int p     = pbase + (t >> 3);
    const int chunk = t & 7;
    const int qb    = chunk * 129;               // chunk*128 + chunk stagger
    const float* pp = &xyz1[((size_t)b * N_ + p) * 3];
    const float px = pp[0], py = pp[1], pz = pp[2];

    float d[4] = {1e30f, 1e30f, 1e30f, 1e30f};
    int  id[4] = {0, 0, 0, 0};

    for (int i = 0; i < 128; i += 4) {
        float dd[4];
        #pragma unroll
        for (int u = 0; u < 4; ++u) {
            const float4 c = q[qb + i + u];
            const float dx = px - c.x, dy = py - c.y, dz = pz - c.z;
            dd[u] = fmaf(dx, dx, fmaf(dy, dy, dz * dz));
        }
        const float m4 = fminf(fminf(dd[0], dd[1]), fminf(dd[2], dd[3]));
        if (__ballot(m4 < d[3])) {               // scalar skip of insert ladder
            #pragma unroll
            for (int u = 0; u < 4; ++u) {
                const float e = dd[u];
                const int  ei = (chunk << 7) + i + u;
                INSERT4(e, ei);
            }
        }
    }

    // merge the 8 chunks (chunk bits are lane bits 0..2):
    // read ALL partner state first, THEN insert (pre-insert snapshot).
    #pragma unroll
    for (int msk = 1; msk <= 4; msk <<= 1) {
        float e0 = __shfl_xor(d[0], msk), e1 = __shfl_xor(d[1], msk);
        float e2 = __shfl_xor(d[2], msk), e3 = __shfl_xor(d[3], msk);
        int   j0 = __shfl_xor(id[0], msk), j1 = __shfl_xor(id[1], msk);
        int   j2 = __shfl_xor(id[2], msk), j3 = __shfl_xor(id[3], msk);
        INSERT4(e0, j0); INSERT4(e1, j1); INSERT4(e2, j2); INSERT4(e3, j3);
    }

    if (chunk == 0) {
        const double px6 = px, py6 = py, pz6 = pz;
        double rd[4]; int ri[4];
        #pragma unroll
        for (int j = 0; j < 4; ++j) {
            const int s = id[j]; ri[j] = s;
            const float4 c = q[s + (s >> 7)];
            const double dx = px6 - (double)c.x, dy = py6 - (double)c.y, dz = pz6 - (double)c.z;
            rd[j] = dx * dx + dy * dy + dz * dz;
        }
        CSWAP(0, 1); CSWAP(2, 3); CSWAP(0, 2); CSWAP(1, 3); CSWAP(1, 2);
        const float r0 = 1.0f / ((float)rd[0] + INTERP_EPS_);
        const float r1 = 1.0f / ((float)rd[1] + INTERP_EPS_);
        const float r2 = 1.0f / ((float)rd[2] + INTERP_EPS_);
        const float rs = r0 + r1 + r2;
        const int base = (b * N_ + p) * 3;
        idx_out[base] = ri[0]; idx_out[base + 1] = ri[1]; idx_out[base + 2] = ri[2];
        w_out[base] = r0 / rs; w_out[base + 1] = r1 / rs; w_out[base + 2] = r2 / rs;
    }
}

// ---------------------------------------------------------------------------
// gemm1: fused {interp-gather, concat, GEMM 65536x384 @ w1^T, BN+ReLU} -> h f16
// 128x256 tile, BK=32, 4 waves (2x2), wave tile 64x128, mfma_f32_16x16x32_f16
// ---------------------------------------------------------------------------
__device__ __forceinline__ void mfma_step1(const f16* As, const f16* Bs,
                                           f32x4 (&acc)[4][8],
                                           int wr, int wc, int lrow, int lhi)
{
    f16x8 af[4], bf[8];
    #pragma unroll
    for (int m = 0; m < 4; ++m)
        af[m] = *(const f16x8*)&As[(wr * 64 + m * 16 + lrow) * 32 + lhi * 8];
    #pragma unroll
    for (int n = 0; n < 8; ++n)
        bf[n] = *(const f16x8*)&Bs[(wc * 128 + n * 16 + lrow) * 32 + lhi * 8];
    #pragma unroll
    for (int m = 0; m < 4; ++m)
        #pragma unroll
        for (int n = 0; n < 8; ++n)
            acc[m][n] = __builtin_amdgcn_mfma_f32_16x16x32_f16(af[m], bf[n], acc[m][n], 0, 0, 0);
}

__global__ __launch_bounds__(256, 2) void gemm1_kernel(
    const float* __restrict__ points1, const float* __restrict__ points2,
    const int* __restrict__ idx, const float* __restrict__ wts,
    const f16* __restrict__ w1f,
    const float* __restrict__ sc1v, const float* __restrict__ sh1v,
    f16* __restrict__ h)
{
    __shared__ __align__(16) f16 As[128 * 32];
    __shared__ __align__(16) f16 Bs[256 * 32];

    const int t = threadIdx.x;
    const int w = t >> 6;
    const int lane = t & 63;
    const int wr = w >> 1, wc = w & 1;
    const int lrow = lane & 15, lhi = lane >> 4;
    const int rowbase = blockIdx.x * 128;

    // staging role: 2 threads per row, khalf = which 16-wide k-half
    const int srow = t >> 1, khalf = t & 1;
    const int R = rowbase + srow;
    const int bb = R >> 14;
    const int mb = R * 3;
    const int i0 = idx[mb], i1 = idx[mb + 1], i2 = idx[mb + 2];
    const float w0 = wts[mb], w1w = wts[mb + 1], w2w = wts[mb + 2];
    const float* p2b = points2 + (size_t)bb * S_ * C2_;
    const float* p1r = points1 + (size_t)R * C1_;
    f16* asrow = &As[srow * 32 + khalf * 16];

    f32x4 acc[4][8] = {};

    // phase A: k in [0,128) from points1
    for (int kb = 0; kb < C1_; kb += 32) {
        __syncthreads();
        const float* src = p1r + kb + khalf * 16;
        #pragma unroll
        for (int g4 = 0; g4 < 4; ++g4) {
            const float4 v = *(const float4*)(src + g4 * 4);
            f16x4 o = {(f16)v.x, (f16)v.y, (f16)v.z, (f16)v.w};
            *(f16x4*)(asrow + g4 * 4) = o;
        }
        #pragma unroll
        for (int j = 0; j < 4; ++j) {
            const int c = j * 256 + t;
            GLD16(w1f + (size_t)(c >> 2) * CIN_ + kb + (c & 3) * 8,
                  (char*)Bs + (j * 4096 + w * 1024));
        }
        __syncthreads();
        mfma_step1(As, Bs, acc, wr, wc, lrow, lhi);
    }

    // phase B: k in [128,384) = 3-NN interpolation of points2
    for (int kb = C1_; kb < CIN_; kb += 32) {
        __syncthreads();
        const int c0 = (kb - C1_) + khalf * 16;
        #pragma unroll
        for (int g4 = 0; g4 < 4; ++g4) {
            const int c = c0 + g4 * 4;
            const float4 f0 = *(const float4*)&p2b[(size_t)i0 * C2_ + c];
            const float4 f1 = *(const float4*)&p2b[(size_t)i1 * C2_ + c];
            const float4 f2 = *(const float4*)&p2b[(size_t)i2 * C2_ + c];
            const float x = fmaf(w0, f0.x, fmaf(w1w, f1.x, w2w * f2.x));
            const float y = fmaf(w0, f0.y, fmaf(w1w, f1.y, w2w * f2.y));
            const float z = fmaf(w0, f0.z, fmaf(w1w, f1.z, w2w * f2.z));
            const float u = fmaf(w0, f0.w, fmaf(w1w, f1.w, w2w * f2.w));
            f16x4 o = {(f16)x, (f16)y, (f16)z, (f16)u};
            *(f16x4*)(asrow + g4 * 4) = o;
        }
        #pragma unroll
        for (int j = 0; j < 4; ++j) {
            const int c = j * 256 + t;
            GLD16(w1f + (size_t)(c >> 2) * CIN_ + kb + (c & 3) * 8,
                  (char*)Bs + (j * 4096 + w * 1024));
        }
        __syncthreads();
        mfma_step1(As, Bs, acc, wr, wc, lrow, lhi);
    }

    // epilogue: BN+ReLU, store f16
    #pragma unroll
    for (int n = 0; n < 8; ++n) {
        const int col = wc * 128 + n * 16 + lrow;
        const float sc = sc1v[col], sh = sh1v[col];
        #pragma unroll
        for (int m = 0; m < 4; ++m) {
            const int row0 = rowbase + wr * 64 + m * 16 + lhi * 4;
            #pragma unroll
            for (int i = 0; i < 4; ++i) {
                const float v = fmaxf(fmaf(acc[m][n][i], sc, sh), 0.0f);
                h[(size_t)(row0 + i) * H1_ + col] = (f16)v;
            }
        }
    }
}

// ---------------------------------------------------------------------------
// gemm2: 65536x256 @ w2^T + BN + ReLU -> out f32. 128x128 tile, BK=32.
// ---------------------------------------------------------------------------
__global__ __launch_bounds__(256, 2) void gemm2_kernel(
    const f16* __restrict__ hin, const f16* __restrict__ w2f,
    const float* __restrict__ sc2v, const float* __restrict__ sh2v,
    float* __restrict__ out)
{
    __shared__ __align__(16) f16 As[128 * 32];
    __shared__ __align__(16) f16 Bs[128 * 32];

    const int t = threadIdx.x;
    const int w = t >> 6;
    const int lane = t & 63;
    const int wr = w >> 1, wc = w & 1;
    const int lrow = lane & 15, lhi = lane >> 4;
    const int rowbase = blockIdx.x * 128;

    f32x4 acc[4][4] = {};

    for (int kb = 0; kb < H1_; kb += 32) {
        __syncthreads();
        #pragma unroll
        for (int j = 0; j < 2; ++j) {
            const int c = j * 256 + t;
            GLD16(hin + (size_t)(rowbase + (c >> 2)) * H1_ + kb + (c & 3) * 8,
                  (char*)As + (j * 4096 + w * 1024));
            GLD16(w2f + (size_t)(c >> 2) * H1_ + kb + (c & 3) * 8,
                  (char*)Bs + (j * 4096 + w * 1024));
        }
        __syncthreads();
        f16x8 af[4], bf[4];
        #pragma unroll
        for (int m = 0; m < 4; ++m)
            af[m] = *(const f16x8*)&As[(wr * 64 + m * 16 + lrow) * 32 + lhi * 8];
        #pragma unroll
        for (int n = 0; n < 4; ++n)
            bf[n] = *(const f16x8*)&Bs[(wc * 64 + n * 16 + lrow) * 32 + lhi * 8];
        #pragma unroll
        for (int m = 0; m < 4; ++m)
            #pragma unroll
            for (int n = 0; n < 4; ++n)
                acc[m][n] = __builtin_amdgcn_mfma_f32_16x16x32_f16(af[m], bf[n], acc[m][n], 0, 0, 0);
    }

    #pragma unroll
    for (int n = 0; n < 4; ++n) {
        const int col = wc * 64 + n * 16 + lrow;
        const float sc = sc2v[col], sh = sh2v[col];
        #pragma unroll
        for (int m = 0; m < 4; ++m) {
            const int row0 = rowbase + wr * 64 + m * 16 + lhi * 4;
            #pragma unroll
            for (int i = 0; i < 4; ++i) {
                out[(size_t)(row0 + i) * H2_ + col] = fmaxf(fmaf(acc[m][n][i], sc, sh), 0.0f);
            }
        }
    }
}

// ---------------------------------------------------------------------------
extern "C" void kernel_launch(void* const* d_in, const int* in_sizes, int n_in,
                              void* d_out, int out_size, void* d_ws, size_t ws_size,
                              hipStream_t stream) {
    const float* xyz1    = (const float*)d_in[0];
    const float* xyz2    = (const float*)d_in[1];
    const float* points1 = (const float*)d_in[2];
    const float* points2 = (const float*)d_in[3];
    const float* w1      = (const float*)d_in[4];
    const float* g1      = (const float*)d_in[5];
    const float* b1      = (const float*)d_in[6];
    const float* m1      = (const float*)d_in[7];
    const float* v1      = (const float*)d_in[8];
    const float* w2      = (const float*)d_in[9];
    const float* g2      = (const float*)d_in[10];
    const float* b2      = (const float*)d_in[11];
    const float* m2      = (const float*)d_in[12];
    const float* v2      = (const float*)d_in[13];
    float* out = (float*)d_out;

    char* ws = (char*)d_ws;
    int*   idx_ws = (int*)(ws + WS_IDX);
    float* w_ws   = (float*)(ws + WS_W);
    f16*   h_ws   = (f16*)(ws + WS_H);
    f16*   w1f    = (f16*)(ws + WS_W1F);
    f16*   w2f    = (f16*)(ws + WS_W2F);
    float* sc1    = (float*)(ws + WS_SC1);
    float* sh1    = (float*)(ws + WS_SH1);
    float* sc2    = (float*)(ws + WS_SC2);
    float* sh2    = (float*)(ws + WS_SH2);

    topk_kernel<<<dim3(B_ * (N_ / 32)), dim3(256), 0, stream>>>(xyz1, xyz2, idx_ws, w_ws);
    prep_kernel<<<dim3(514), dim3(256), 0, stream>>>(w1, w2, g1, b1, m1, v1,
                                                     g2, b2, m2, v2,
                                                     w1f, w2f, sc1, sh1, sc2, sh2);
    gemm1_kernel<<<dim3(512), dim3(256), 0, stream>>>(points1, points2, idx_ws, w_ws,
                                                      w1f, sc1, sh1, h_ws);
    gemm2_kernel<<<dim3(512), dim3(256), 0, stream>>>(h_ws, w2f, sc2, sh2, out);
}

// Round 7
// 185.890 us; speedup vs baseline: 2.6068x; 1.0986x over previous
//
#include <hip/hip_runtime.h>
#include <math.h>

#define B_    4
#define N_    16384
#define S_    1024
#define C1_   128
#define C2_   256
#define CIN_  384
#define H1_   256
#define H2_   128
#define BN_EPS_     1e-5f
#define INTERP_EPS_ 1e-8f

typedef _Float16 f16;
typedef _Float16 f16x4 __attribute__((ext_vector_type(4)));
typedef _Float16 f16x8 __attribute__((ext_vector_type(8)));
typedef float    f32x4 __attribute__((ext_vector_type(4)));
typedef unsigned int u32;

// async global->LDS, 16B per lane; LDS dest = wave-uniform base + lane*16
#define GLD16(g, l) \
  __builtin_amdgcn_global_load_lds((const __attribute__((address_space(1))) void*)(g), \
                                   (__attribute__((address_space(3))) void*)(l), 16, 0, 0)

// ---- ws layout (bytes); total 68.42 MB < 68.68 MB proven in round 0 ----
#define WS_IDXP 0            // u32 [65536] packed (i0 | i1<<10 | i2<<20)
#define WS_W    262144       // f32 [65536][3]
#define WS_XI   1048576      // f16 [65536][256] interpolated features
#define WS_H    34603008     // f16 [65536][256] hidden
#define WS_W1F  68157440     // f16 [256][384]
#define WS_W2F  68354048     // f16 [128][256]
#define WS_SC1  68419584
#define WS_SH1  68420608
#define WS_SC2  68421632
#define WS_SH2  68422144

// ---------------------------------------------------------------------------
// prep: w1,w2 -> f16; fold BN into (scale, shift)
// ---------------------------------------------------------------------------
__global__ __launch_bounds__(256) void prep_kernel(
    const float* __restrict__ w1, const float* __restrict__ w2,
    const float* __restrict__ g1, const float* __restrict__ b1,
    const float* __restrict__ m1, const float* __restrict__ v1,
    const float* __restrict__ g2, const float* __restrict__ b2,
    const float* __restrict__ m2, const float* __restrict__ v2,
    f16* __restrict__ w1f, f16* __restrict__ w2f,
    float* __restrict__ sc1, float* __restrict__ sh1,
    float* __restrict__ sc2, float* __restrict__ sh2)
{
    const int t = blockIdx.x * 256 + threadIdx.x;
    if (t < 98304) {
        w1f[t] = (f16)w1[t];
    } else if (t < 131072) {
        w2f[t - 98304] = (f16)w2[t - 98304];
    } else if (t < 131328) {
        const int c = t - 131072;
        const float s = g1[c] / sqrtf(v1[c] + BN_EPS_);
        sc1[c] = s; sh1[c] = b1[c] - m1[c] * s;
    } else if (t < 131456) {
        const int c = t - 131328;
        const float s = g2[c] / sqrtf(v2[c] + BN_EPS_);
        sc2[c] = s; sh2[c] = b2[c] - m2[c] * s;
    }
}

// ---------------------------------------------------------------------------
// topk: 8 threads/point, 128 candidates each. Branchless scan:
// key = (f32 dist bits & ~0x3FF) | idx  (uint-monotone, unique, stable ties).
// Sorted top-5 via v_min_u32/v_max_u32 compare-exchange chain (9 ops/cand).
// Snapshot-then-insert shuffle merge. f64 refine of 5 survivors -> exact
// ordering vs the np reference (misselection needs a triple collision
// within 2^-13 relative distance -> negligible).
// ---------------------------------------------------------------------------
__device__ __forceinline__ u32 umin_(u32 a, u32 b) { return a < b ? a : b; }
__device__ __forceinline__ u32 umax_(u32 a, u32 b) { return a > b ? a : b; }

#define KINS(k) do { \
    u32 c1 = umax_(s0, (k)); s0 = umin_(s0, (k)); \
    u32 c2 = umax_(s1, c1);  s1 = umin_(s1, c1);  \
    u32 c3 = umax_(s2, c2);  s2 = umin_(s2, c2);  \
    u32 c4 = umax_(s3, c3);  s3 = umin_(s3, c3);  \
    s4 = umin_(s4, c4); } while (0)

#define CSWAP(a_, b_) do { \
    if (rd[b_] < rd[a_] || (rd[b_] == rd[a_] && ri[b_] < ri[a_])) { \
      double td = rd[a_]; rd[a_] = rd[b_]; rd[b_] = td; \
      int ti = ri[a_]; ri[a_] = ri[b_]; ri[b_] = ti; } } while (0)

__global__ __launch_bounds__(256) void topk_kernel(
    const float* __restrict__ xyz1, const float* __restrict__ xyz2,
    u32* __restrict__ idxp_out, float* __restrict__ w_out)
{
    // float4 (x,y,z,pad); +1 float4 stagger per 128-chunk tiles all 32 banks
    __shared__ float4 q[S_ + 8];
    const int b     = blockIdx.x >> 9;           // 512 blocks/batch, 32 pts each
    const int pbase = (blockIdx.x & 511) << 5;
    const int t     = threadIdx.x;

    for (int i = t; i < S_; i += 256) {
        const float* s = &xyz2[((size_t)b * S_ + i) * 3];
        float4 v; v.x = s[0]; v.y = s[1]; v.z = s[2]; v.w = 0.0f;
        q[i + (i >> 7)] = v;
    }
    __syncthreads();

    const int p     = pbase + (t >> 3);
    const int chunk = t & 7;
    const int qb    = chunk * 129;               // chunk*128 + chunk stagger
    const int ebase = chunk << 7;
    const float* pp = &xyz1[((size_t)b * N_ + p) * 3];
    const float px = pp[0], py = pp[1], pz = pp[2];

    u32 s0 = 0xFFFFFFFFu, s1 = 0xFFFFFFFFu, s2 = 0xFFFFFFFFu,
        s3 = 0xFFFFFFFFu, s4 = 0xFFFFFFFFu;

    for (int i = 0; i < 128; i += 4) {
        #pragma unroll
        for (int u = 0; u < 4; ++u) {
            const float4 c = q[qb + i + u];
            const float dx = px - c.x, dy = py - c.y, dz = pz - c.z;
            const float dd = fmaf(dx, dx, fmaf(dy, dy, dz * dz));
            const u32 k = (__float_as_uint(dd) & 0xFFFFFC00u) | (u32)(ebase + i + u);
            KINS(k);
        }
    }

    // merge the 8 chunks (chunk bits = lane bits 0..2):
    // snapshot ALL partner keys BEFORE inserting (round-4 lesson).
    #pragma unroll
    for (int msk = 1; msk <= 4; msk <<= 1) {
        u32 e0 = __shfl_xor(s0, msk), e1 = __shfl_xor(s1, msk);
        u32 e2 = __shfl_xor(s2, msk), e3 = __shfl_xor(s3, msk);
        u32 e4 = __shfl_xor(s4, msk);
        KINS(e0); KINS(e1); KINS(e2); KINS(e3); KINS(e4);
    }

    if (chunk == 0) {
        const double px6 = px, py6 = py, pz6 = pz;
        double rd[5]; int ri[5];
        const u32 ks[5] = {s0, s1, s2, s3, s4};
        #pragma unroll
        for (int j = 0; j < 5; ++j) {
            const int si = (int)(ks[j] & 1023u); ri[j] = si;
            const float4 c = q[si + (si >> 7)];
            const double dx = px6 - (double)c.x, dy = py6 - (double)c.y, dz = pz6 - (double)c.z;
            rd[j] = dx * dx + dy * dy + dz * dz;
        }
        // insertion-sort network (nearly sorted input), lex (d, idx)
        CSWAP(0,1); CSWAP(1,2); CSWAP(0,1); CSWAP(2,3); CSWAP(1,2);
        CSWAP(0,1); CSWAP(3,4); CSWAP(2,3); CSWAP(1,2); CSWAP(0,1);
        const float r0 = 1.0f / ((float)rd[0] + INTERP_EPS_);
        const float r1 = 1.0f / ((float)rd[1] + INTERP_EPS_);
        const float r2 = 1.0f / ((float)rd[2] + INTERP_EPS_);
        const float rs = r0 + r1 + r2;
        const int row = b * N_ + p;
        idxp_out[row] = (u32)ri[0] | ((u32)ri[1] << 10) | ((u32)ri[2] << 20);
        w_out[row * 3 + 0] = r0 / rs;
        w_out[row * 3 + 1] = r1 / rs;
        w_out[row * 3 + 2] = r2 / rs;
    }
}

// ---------------------------------------------------------------------------
// interp: 3-NN weighted gather -> xi f16 [65536][256]. Fully coalesced:
// 8 rows/block, 32 lanes/row, 8 cols/lane (2 float4 loads per neighbor).
// points2 (1 MB/batch) is L2-resident.
// ---------------------------------------------------------------------------
__global__ __launch_bounds__(256) void interp_kernel(
    const float* __restrict__ points2, const u32* __restrict__ idxp,
    const float* __restrict__ wts, f16* __restrict__ xi)
{
    const int row  = blockIdx.x * 8 + (threadIdx.x >> 5);
    const int lane = threadIdx.x & 31;
    const int bb   = row >> 14;
    const u32 u    = idxp[row];
    const int i0 = (int)(u & 1023u), i1 = (int)((u >> 10) & 1023u), i2 = (int)(u >> 20);
    const float w0 = wts[row * 3], w1w = wts[row * 3 + 1], w2w = wts[row * 3 + 2];
    const float* p2b = points2 + (size_t)bb * S_ * C2_;
    const int c0 = lane * 8;

    const float4 a0 = *(const float4*)&p2b[i0 * C2_ + c0];
    const float4 a1 = *(const float4*)&p2b[i0 * C2_ + c0 + 4];
    const float4 b0 = *(const float4*)&p2b[i1 * C2_ + c0];
    const float4 b1 = *(const float4*)&p2b[i1 * C2_ + c0 + 4];
    const float4 d0 = *(const float4*)&p2b[i2 * C2_ + c0];
    const float4 d1 = *(const float4*)&p2b[i2 * C2_ + c0 + 4];

    f16x8 o;
    o[0] = (f16)fmaf(w0, a0.x, fmaf(w1w, b0.x, w2w * d0.x));
    o[1] = (f16)fmaf(w0, a0.y, fmaf(w1w, b0.y, w2w * d0.y));
    o[2] = (f16)fmaf(w0, a0.z, fmaf(w1w, b0.z, w2w * d0.z));
    o[3] = (f16)fmaf(w0, a0.w, fmaf(w1w, b0.w, w2w * d0.w));
    o[4] = (f16)fmaf(w0, a1.x, fmaf(w1w, b1.x, w2w * d1.x));
    o[5] = (f16)fmaf(w0, a1.y, fmaf(w1w, b1.y, w2w * d1.y));
    o[6] = (f16)fmaf(w0, a1.z, fmaf(w1w, b1.z, w2w * d1.z));
    o[7] = (f16)fmaf(w0, a1.w, fmaf(w1w, b1.w, w2w * d1.w));
    *(f16x8*)&xi[(size_t)row * C2_ + c0] = o;
}

// ---------------------------------------------------------------------------
// gemm1: GEMM 65536x384 @ w1^T + BN + ReLU -> h f16.
// 128x256 tile, BK=32, 4 waves (2x2), wave tile 64x128, mfma_f32_16x16x32_f16.
// Phase A (k<128): points1 f32 VALU-staged; phase B (k>=128): xi via GLD16.
// ---------------------------------------------------------------------------
__device__ __forceinline__ void mfma_step1(const f16* As, const f16* Bs,
                                           f32x4 (&acc)[4][8],
                                           int wr, int wc, int lrow, int lhi)
{
    f16x8 af[4], bf[8];
    #pragma unroll
    for (int m = 0; m < 4; ++m)
        af[m] = *(const f16x8*)&As[(wr * 64 + m * 16 + lrow) * 32 + lhi * 8];
    #pragma unroll
    for (int n = 0; n < 8; ++n)
        bf[n] = *(const f16x8*)&Bs[(wc * 128 + n * 16 + lrow) * 32 + lhi * 8];
    #pragma unroll
    for (int m = 0; m < 4; ++m)
        #pragma unroll
        for (int n = 0; n < 8; ++n)
            acc[m][n] = __builtin_amdgcn_mfma_f32_16x16x32_f16(af[m], bf[n], acc[m][n], 0, 0, 0);
}

__global__ __launch_bounds__(256, 2) void gemm1_kernel(
    const float* __restrict__ points1, const f16* __restrict__ xi,
    const f16* __restrict__ w1f,
    const float* __restrict__ sc1v, const float* __restrict__ sh1v,
    f16* __restrict__ h)
{
    __shared__ __align__(16) f16 As[128 * 32];
    __shared__ __align__(16) f16 Bs[256 * 32];

    const int t = threadIdx.x;
    const int w = t >> 6;
    const int lane = t & 63;
    const int wr = w >> 1, wc = w & 1;
    const int lrow = lane & 15, lhi = lane >> 4;
    const int rowbase = blockIdx.x * 128;

    // phase-A staging role: 2 threads per row, khalf = which 16-wide k-half
    const int srow = t >> 1, khalf = t & 1;
    const float* p1r = points1 + (size_t)(rowbase + srow) * C1_;
    f16* asrow = &As[srow * 32 + khalf * 16];

    f32x4 acc[4][8] = {};

    // phase A: k in [0,128) from points1 (f32 -> f16 VALU staging)
    for (int kb = 0; kb < C1_; kb += 32) {
        __syncthreads();
        const float* src = p1r + kb + khalf * 16;
        #pragma unroll
        for (int g4 = 0; g4 < 4; ++g4) {
            const float4 v = *(const float4*)(src + g4 * 4);
            f16x4 o = {(f16)v.x, (f16)v.y, (f16)v.z, (f16)v.w};
            *(f16x4*)(asrow + g4 * 4) = o;
        }
        #pragma unroll
        for (int j = 0; j < 4; ++j) {
            const int c = j * 256 + t;
            GLD16(w1f + (size_t)(c >> 2) * CIN_ + kb + (c & 3) * 8,
                  (char*)Bs + (j * 4096 + w * 1024));
        }
        __syncthreads();
        mfma_step1(As, Bs, acc, wr, wc, lrow, lhi);
    }

    // phase B: k in [128,384) from xi (pure GLD16, gemm2-proven pattern)
    for (int kb = C1_; kb < CIN_; kb += 32) {
        __syncthreads();
        const int kk = kb - C1_;
        #pragma unroll
        for (int j = 0; j < 2; ++j) {
            const int c = j * 256 + t;
            GLD16(xi + (size_t)(rowbase + (c >> 2)) * C2_ + kk + (c & 3) * 8,
                  (char*)As + (j * 4096 + w * 1024));
        }
        #pragma unroll
        for (int j = 0; j < 4; ++j) {
            const int c = j * 256 + t;
            GLD16(w1f + (size_t)(c >> 2) * CIN_ + kb + (c & 3) * 8,
                  (char*)Bs + (j * 4096 + w * 1024));
        }
        __syncthreads();
        mfma_step1(As, Bs, acc, wr, wc, lrow, lhi);
    }

    // epilogue: BN+ReLU, store f16
    #pragma unroll
    for (int n = 0; n < 8; ++n) {
        const int col = wc * 128 + n * 16 + lrow;
        const float sc = sc1v[col], sh = sh1v[col];
        #pragma unroll
        for (int m = 0; m < 4; ++m) {
            const int row0 = rowbase + wr * 64 + m * 16 + lhi * 4;
            #pragma unroll
            for (int i = 0; i < 4; ++i) {
                const float v = fmaxf(fmaf(acc[m][n][i], sc, sh), 0.0f);
                h[(size_t)(row0 + i) * H1_ + col] = (f16)v;
            }
        }
    }
}

// ---------------------------------------------------------------------------
// gemm2: 65536x256 @ w2^T + BN + ReLU -> out f32. 128x128 tile, BK=32.
// ---------------------------------------------------------------------------
__global__ __launch_bounds__(256, 2) void gemm2_kernel(
    const f16* __restrict__ hin, const f16* __restrict__ w2f,
    const float* __restrict__ sc2v, const float* __restrict__ sh2v,
    float* __restrict__ out)
{
    __shared__ __align__(16) f16 As[128 * 32];
    __shared__ __align__(16) f16 Bs[128 * 32];

    const int t = threadIdx.x;
    const int w = t >> 6;
    const int lane = t & 63;
    const int wr = w >> 1, wc = w & 1;
    const int lrow = lane & 15, lhi = lane >> 4;
    const int rowbase = blockIdx.x * 128;

    f32x4 acc[4][4] = {};

    for (int kb = 0; kb < H1_; kb += 32) {
        __syncthreads();
        #pragma unroll
        for (int j = 0; j < 2; ++j) {
            const int c = j * 256 + t;
            GLD16(hin + (size_t)(rowbase + (c >> 2)) * H1_ + kb + (c & 3) * 8,
                  (char*)As + (j * 4096 + w * 1024));
            GLD16(w2f + (size_t)(c >> 2) * H1_ + kb + (c & 3) * 8,
                  (char*)Bs + (j * 4096 + w * 1024));
        }
        __syncthreads();
        f16x8 af[4], bf[4];
        #pragma unroll
        for (int m = 0; m < 4; ++m)
            af[m] = *(const f16x8*)&As[(wr * 64 + m * 16 + lrow) * 32 + lhi * 8];
        #pragma unroll
        for (int n = 0; n < 4; ++n)
            bf[n] = *(const f16x8*)&Bs[(wc * 64 + n * 16 + lrow) * 32 + lhi * 8];
        #pragma unroll
        for (int m = 0; m < 4; ++m)
            #pragma unroll
            for (int n = 0; n < 4; ++n)
                acc[m][n] = __builtin_amdgcn_mfma_f32_16x16x32_f16(af[m], bf[n], acc[m][n], 0, 0, 0);
    }

    #pragma unroll
    for (int n = 0; n < 4; ++n) {
        const int col = wc * 64 + n * 16 + lrow;
        const float sc = sc2v[col], sh = sh2v[col];
        #pragma unroll
        for (int m = 0; m < 4; ++m) {
            const int row0 = rowbase + wr * 64 + m * 16 + lhi * 4;
            #pragma unroll
            for (int i = 0; i < 4; ++i) {
                out[(size_t)(row0 + i) * H2_ + col] = fmaxf(fmaf(acc[m][n][i], sc, sh), 0.0f);
            }
        }
    }
}

// ---------------------------------------------------------------------------
extern "C" void kernel_launch(void* const* d_in, const int* in_sizes, int n_in,
                              void* d_out, int out_size, void* d_ws, size_t ws_size,
                              hipStream_t stream) {
    const float* xyz1    = (const float*)d_in[0];
    const float* xyz2    = (const float*)d_in[1];
    const float* points1 = (const float*)d_in[2];
    const float* points2 = (const float*)d_in[3];
    const float* w1      = (const float*)d_in[4];
    const float* g1      = (const float*)d_in[5];
    const float* b1      = (const float*)d_in[6];
    const float* m1      = (const float*)d_in[7];
    const float* v1      = (const float*)d_in[8];
    const float* w2      = (const float*)d_in[9];
    const float* g2      = (const float*)d_in[10];
    const float* b2      = (const float*)d_in[11];
    const float* m2      = (const float*)d_in[12];
    const float* v2      = (const float*)d_in[13];
    float* out = (float*)d_out;

    char* ws = (char*)d_ws;
    u32*   idxp_ws = (u32*)(ws + WS_IDXP);
    float* w_ws    = (float*)(ws + WS_W);
    f16*   xi_ws   = (f16*)(ws + WS_XI);
    f16*   h_ws    = (f16*)(ws + WS_H);
    f16*   w1f     = (f16*)(ws + WS_W1F);
    f16*   w2f     = (f16*)(ws + WS_W2F);
    float* sc1     = (float*)(ws + WS_SC1);
    float* sh1     = (float*)(ws + WS_SH1);
    float* sc2     = (float*)(ws + WS_SC2);
    float* sh2     = (float*)(ws + WS_SH2);

    topk_kernel<<<dim3(B_ * (N_ / 32)), dim3(256), 0, stream>>>(xyz1, xyz2, idxp_ws, w_ws);
    prep_kernel<<<dim3(514), dim3(256), 0, stream>>>(w1, w2, g1, b1, m1, v1,
                                                     g2, b2, m2, v2,
                                                     w1f, w2f, sc1, sh1, sc2, sh2);
    interp_kernel<<<dim3(B_ * N_ / 8), dim3(256), 0, stream>>>(points2, idxp_ws, w_ws, xi_ws);
    gemm1_kernel<<<dim3(512), dim3(256), 0, stream>>>(points1, xi_ws, w1f, sc1, sh1, h_ws);
    gemm2_kernel<<<dim3(512), dim3(256), 0, stream>>>(h_ws, w2f, sc2, sh2, out);
}